// Round 17
// baseline (52.233 us; speedup 1.0000x reference)
//
#include <hip/hip_runtime.h>
#include <hip/hip_bf16.h>
#include <math.h>

#define B_ 2
#define T_ 2048
#define D_ 512
#define H_ 16
#define DH 32
#define L_ 64
#define C_ 32
#define NC 1024    // total chunks
#define VTP 72     // LDS row stride (ushorts) for chunk kernels
#define CSZ 1056   // floats per chunk state tile (33 rows x 32)

typedef __attribute__((ext_vector_type(8))) short bf16x8;
typedef __attribute__((ext_vector_type(4))) float f32x4;
typedef __attribute__((ext_vector_type(4))) unsigned short u16x4;

#define AS1 __attribute__((address_space(1)))
#define AS3 __attribute__((address_space(3)))

__device__ __forceinline__ float bf2f(unsigned short u) {
    union { float f; unsigned int i; } v; v.i = ((unsigned int)u) << 16; return v.f;
}
__device__ __forceinline__ unsigned short f2bf(float f) {
    union { float f; unsigned int u; } v; v.f = f;
    unsigned int u = v.u;
    unsigned int r = u + 0x7FFFu + ((u >> 16) & 1u);
    return (unsigned short)(r >> 16);
}
__device__ __forceinline__ unsigned short f2bf_rne(float f) {
    __hip_bfloat16 h = __float2bfloat16(f);
    union { __hip_bfloat16 h; unsigned short u; } v; v.h = h; return v.u;
}
__device__ __forceinline__ float phi_s(float f) {
    return f > 0.f ? f + 1.f : __expf(f);
}
__device__ __forceinline__ void gload_lds16(const unsigned short* g, unsigned short* l) {
    __builtin_amdgcn_global_load_lds((const AS1 unsigned int*)g, (AS3 unsigned int*)l, 16, 0, 0);
}

// ---- gemm1 + fused chunk_sum: one block = TWO consecutive chunks (128 rows x
// one head's q|k|v). Each wave owns 32 rows -> 12 MFMA per 8 ds_reads (was 6/7),
// W staging per chunk halved. qkvb gets phi(q), phi(k), raw v.
// Epilogue: wave pair (2ci,2ci+1) computes chunk ci's ST -> cSf.
struct __align__(16) ShQ {
    union {
        struct { unsigned short As[2][128][32]; unsigned short Bs[2][96][32]; } g;  // 28672 B
        struct { unsigned short Kt[2][DH][VTP]; unsigned short Vt[2][48][VTP]; } s; // 23040 B
    };
};

__global__ __launch_bounds__(256) void gemm_qkv_cs(const float* __restrict__ x,
                                                   const float* __restrict__ W,
                                                   unsigned short* __restrict__ qkvb,
                                                   float* __restrict__ cSf)
{
    __shared__ ShQ sh;
    const int tid = threadIdx.x;
    const int lane = tid & 63;
    const int w = tid >> 6;            // wave = 32-row strip
    const int chunk0 = blockIdx.x * 2;
    const int c0 = chunk0 & 31;
    const int h = (chunk0 >> 5) & 15;
    const int b = chunk0 >> 9;
    const size_t R0 = (size_t)(b * T_ + c0 * L_);

    // staging map: thread -> (row sr 0..31, float col sc)
    const int sr = tid >> 3;
    const int sc = (tid & 7) * 4;
    const float* ax  = x + (R0 + sr) * 512 + sc;
    const float* wgq = W + ((size_t)(h * DH) + sr) * 512 + sc;
    const float* wgk = W + ((size_t)(D_ + h * DH) + sr) * 512 + sc;
    const float* wgv = W + ((size_t)(2 * D_ + h * DH) + sr) * 512 + sc;

    f32x4 aL[4], wL[3];
    auto load_stage = [&](int k0) {
        #pragma unroll
        for (int i = 0; i < 4; ++i)
            aL[i] = *(const f32x4*)(ax + k0 + (size_t)(i * 32) * 512);
        wL[0] = *(const f32x4*)(wgq + k0);
        wL[1] = *(const f32x4*)(wgk + k0);
        wL[2] = *(const f32x4*)(wgv + k0);
    };
    auto cvt4 = [](f32x4 v) {
        u16x4 o;
        o.x = f2bf_rne(v[0]); o.y = f2bf_rne(v[1]);
        o.z = f2bf_rne(v[2]); o.w = f2bf_rne(v[3]);
        return o;
    };
    auto write_stage = [&](int buf) {
        #pragma unroll
        for (int i = 0; i < 4; ++i)
            *(u16x4*)&sh.g.As[buf][sr + i * 32][sc] = cvt4(aL[i]);
        *(u16x4*)&sh.g.Bs[buf][sr][sc]      = cvt4(wL[0]);
        *(u16x4*)&sh.g.Bs[buf][sr + 32][sc] = cvt4(wL[1]);
        *(u16x4*)&sh.g.Bs[buf][sr + 64][sc] = cvt4(wL[2]);
    };

    f32x4 acc[2][6];
    #pragma unroll
    for (int m = 0; m < 2; ++m)
        #pragma unroll
        for (int n = 0; n < 6; ++n)
            acc[m][n] = (f32x4){0.f, 0.f, 0.f, 0.f};

    const int rr = lane & 15;
    const int fg = lane >> 4;
    const int kb = fg * 8;

    load_stage(0);
    write_stage(0);
    __syncthreads();
    int cur = 0;
    for (int k0 = 0; k0 < 512; k0 += 32) {
        const bool more = k0 + 32 < 512;
        if (more) load_stage(k0 + 32);
        bf16x8 af[2], bfr[6];
        #pragma unroll
        for (int mm = 0; mm < 2; ++mm)
            af[mm] = *(const bf16x8*)&sh.g.As[cur][w * 32 + mm * 16 + rr][kb];
        #pragma unroll
        for (int n = 0; n < 6; ++n)
            bfr[n] = *(const bf16x8*)&sh.g.Bs[cur][n * 16 + rr][kb];
        #pragma unroll
        for (int mm = 0; mm < 2; ++mm)
            #pragma unroll
            for (int n = 0; n < 6; ++n)
                acc[mm][n] = __builtin_amdgcn_mfma_f32_16x16x32_bf16(af[mm], bfr[n], acc[mm][n], 0, 0, 0);
        if (more) write_stage(cur ^ 1);
        __syncthreads();
        cur ^= 1;
    }

    // ---- epilogue A: write qkv panel to global; q,k tiles get phi PRE-applied
    {
        const int colbase[6] = { h * DH, h * DH + 16,
                                 D_ + h * DH, D_ + h * DH + 16,
                                 2 * D_ + h * DH, 2 * D_ + h * DH + 16 };
        #pragma unroll
        for (int mm = 0; mm < 2; ++mm)
            #pragma unroll
            for (int n = 0; n < 6; ++n)
                #pragma unroll
                for (int j = 0; j < 4; ++j) {
                    size_t row = R0 + w * 32 + mm * 16 + fg * 4 + j;
                    float v = (n < 4) ? phi_s(acc[mm][n][j]) : acc[mm][n][j];
                    qkvb[row * 1536 + colbase[n] + rr] = f2bf(v);
                }
    }

    // ---- epilogue B: transpose phi(K), V into LDS (staging dead after last
    // barrier), then chunk_sum MFMAs: wave pair (2ci,2ci+1) -> chunk ci.
    {
        const int ci = w >> 1;
        const int wl = w & 1;
        #pragma unroll
        for (int mm = 0; mm < 2; ++mm)
            #pragma unroll
            for (int j = 0; j < 4; ++j) {
                int t = wl * 32 + mm * 16 + fg * 4 + j;
                sh.s.Kt[ci][rr][t]      = f2bf(phi_s(acc[mm][2][j]));
                sh.s.Kt[ci][16 + rr][t] = f2bf(phi_s(acc[mm][3][j]));
                sh.s.Vt[ci][rr][t]      = f2bf(acc[mm][4][j]);
                sh.s.Vt[ci][16 + rr][t] = f2bf(acc[mm][5][j]);
                if (rr == 0) sh.s.Vt[ci][32][t] = 0x3F80;   // ones row
            }
    }
    __syncthreads();

    {
        const int ci = w >> 1;
        const int chunk = chunk0 + ci;
        float* outp = cSf + (size_t)chunk * CSZ;
        const int nm = (w & 1) ? 1 : 2;          // odd wave: m=1; even wave: m=0 and m=2
        #pragma unroll
        for (int mi = 0; mi < 2; ++mi) {
            if (mi < nm) {
                int m = (w & 1) ? 1 : mi * 2;    // even: 0,2 ; odd: 1
                f32x4 a2[2];
                a2[0] = (f32x4){0.f, 0.f, 0.f, 0.f};
                a2[1] = (f32x4){0.f, 0.f, 0.f, 0.f};
                #pragma unroll
                for (int ks = 0; ks < 2; ++ks) {
                    int toff = fg * 8 + ks * 32;
                    bf16x8 av = *(const bf16x8*)&sh.s.Vt[ci][m * 16 + rr][toff];
                    #pragma unroll
                    for (int n = 0; n < 2; ++n) {
                        bf16x8 bkk = *(const bf16x8*)&sh.s.Kt[ci][n * 16 + rr][toff];
                        a2[n] = __builtin_amdgcn_mfma_f32_16x16x32_bf16(av, bkk, a2[n], 0, 0, 0);
                    }
                }
                if (m < 2) {
                    #pragma unroll
                    for (int n = 0; n < 2; ++n)
                        #pragma unroll
                        for (int r = 0; r < 4; ++r)
                            outp[(m * 16 + fg * 4 + r) * 32 + n * 16 + rr] = a2[n][r];
                } else if (fg == 0) {
                    #pragma unroll
                    for (int n = 0; n < 2; ++n)
                        outp[32 * 32 + n * 16 + rr] = a2[n][0];
                }
            }
        }
    }
}

// ---- gemm2: out = attn @ w_out^T. A bf16 via global_load_lds; W fp32 reg-staged.
template<int BM, bool AF32, bool OUT_BF16>
__global__ __launch_bounds__(256) void gemm_nt(const void* __restrict__ Aptr,
                                               const float* __restrict__ Wf,
                                               void* __restrict__ Cout,
                                               int N, int K)
{
    constexpr int MF = BM / 32;
    constexpr int AF4 = BM / 32;
    __shared__ unsigned short As[2][BM][32];
    __shared__ unsigned short Bs[2][128][32];
    const int tid = threadIdx.x;
    const int lane = tid & 63;
    const int wave = tid >> 6;
    const int wr = wave >> 1;
    const int wc = wave & 1;
    const size_t bm = (size_t)blockIdx.x * BM;
    const size_t bn = (size_t)blockIdx.y * 128;

    const int r8 = lane >> 3;
    const int c4 = (lane & 7) * 4;
    const int lrow = lane >> 2;
    const int lcol = (lane & 3) * 8;

    const float* agf = nullptr;
    const unsigned short* agb = nullptr;
    if constexpr (AF32) agf = (const float*)Aptr + (bm + wave * (BM / 4) + r8) * (size_t)K + c4;
    else                agb = (const unsigned short*)Aptr + (bm + wave * (BM / 4) + lrow) * (size_t)K + lcol;
    const float* wgf = Wf + (bn + wave * 32 + r8) * (size_t)K + c4;

    f32x4 aL[AF4];
    f32x4 wL[4];

    auto load_stage = [&](int buf, int k0) {
        if constexpr (AF32) {
            #pragma unroll
            for (int i = 0; i < AF4; ++i)
                aL[i] = *(const f32x4*)(agf + k0 + (size_t)(i * 8) * K);
        } else {
            gload_lds16(agb + k0, &As[buf][wave * (BM / 4)][0]);
            if constexpr (BM / 4 == 32)
                gload_lds16(agb + (size_t)16 * K + k0, &As[buf][wave * (BM / 4) + 16][0]);
        }
        #pragma unroll
        for (int i = 0; i < 4; ++i)
            wL[i] = *(const f32x4*)(wgf + k0 + (size_t)(i * 8) * K);
    };
    auto write_stage = [&](int buf) {
        if constexpr (AF32) {
            #pragma unroll
            for (int i = 0; i < AF4; ++i) {
                u16x4 o;
                o.x = f2bf_rne(aL[i][0]); o.y = f2bf_rne(aL[i][1]);
                o.z = f2bf_rne(aL[i][2]); o.w = f2bf_rne(aL[i][3]);
                *(u16x4*)&As[buf][wave * (BM / 4) + r8 + i * 8][c4] = o;
            }
        }
        #pragma unroll
        for (int i = 0; i < 4; ++i) {
            u16x4 o;
            o.x = f2bf_rne(wL[i][0]); o.y = f2bf_rne(wL[i][1]);
            o.z = f2bf_rne(wL[i][2]); o.w = f2bf_rne(wL[i][3]);
            *(u16x4*)&Bs[buf][wave * 32 + r8 + i * 8][c4] = o;
        }
    };

    f32x4 acc[MF][4];
    #pragma unroll
    for (int m = 0; m < MF; ++m)
        #pragma unroll
        for (int n = 0; n < 4; ++n)
            acc[m][n] = (f32x4){0.f, 0.f, 0.f, 0.f};

    const int rr = lane & 15;
    const int kb = (lane >> 4) * 8;

    load_stage(0, 0);
    write_stage(0);
    __syncthreads();
    int cur = 0;
    for (int k0 = 0; k0 < K; k0 += 32) {
        const bool more = k0 + 32 < K;
        if (more) load_stage(cur ^ 1, k0 + 32);
        bf16x8 af[MF], bfr[4];
        #pragma unroll
        for (int m = 0; m < MF; ++m)
            af[m] = *(const bf16x8*)&As[cur][wr * (BM / 2) + m * 16 + rr][kb];
        #pragma unroll
        for (int n = 0; n < 4; ++n)
            bfr[n] = *(const bf16x8*)&Bs[cur][wc * 64 + n * 16 + rr][kb];
        #pragma unroll
        for (int m = 0; m < MF; ++m)
            #pragma unroll
            for (int n = 0; n < 4; ++n)
                acc[m][n] = __builtin_amdgcn_mfma_f32_16x16x32_bf16(af[m], bfr[n], acc[m][n], 0, 0, 0);
        if (more) write_stage(cur ^ 1);
        __syncthreads();
        cur ^= 1;
    }

    const int cr = (lane >> 4) * 4;
    const int cc = lane & 15;
    #pragma unroll
    for (int m = 0; m < MF; ++m)
        #pragma unroll
        for (int n = 0; n < 4; ++n)
            #pragma unroll
            for (int j = 0; j < 4; ++j) {
                size_t row = bm + wr * (BM / 2) + m * 16 + cr + j;
                size_t col = bn + wc * 64 + n * 16 + cc;
                float v = acc[m][n][j];
                if (OUT_BF16) ((unsigned short*)Cout)[row * N + col] = f2bf(v);
                else          ((float*)Cout)[row * N + col] = v;
            }
}

// Exclusive prefix over chunks; emit bf16 state cSt[chunk][e*32+d].
__global__ __launch_bounds__(256) void chunk_scan(const float* __restrict__ cSf,
                                                  unsigned short* __restrict__ cSt)
{
    int idx = blockIdx.x * 256 + threadIdx.x;     // 32*1056 = 33792 exactly
    int bh = idx / CSZ;
    int r  = idx % CSZ;
    const float* src = cSf + (size_t)bh * C_ * CSZ + r;
    unsigned short* dst = cSt + (size_t)bh * C_ * CSZ + r;
    float v[C_];
    #pragma unroll
    for (int c = 0; c < C_; ++c) v[c] = src[(size_t)c * CSZ];
    float acc = 0.f;
    #pragma unroll
    for (int c = 0; c < C_; ++c) {
        dst[(size_t)c * CSZ] = f2bf(acc);
        acc += v[c];
    }
}

// Per-chunk output via MFMA. ONE chunk per block; 4 waves, wave w owns m-tile w.
// qkv holds phi(q)/phi(k) pre-applied (plain fragment loads); V staged in LDS.
__global__ __launch_bounds__(256) void chunk_out(const unsigned short* __restrict__ qkv,
                                                 const unsigned short* __restrict__ cSt,
                                                 unsigned short* __restrict__ attn)
{
    __shared__ unsigned short Vt[48][VTP];
    __shared__ unsigned short Am[4][16][VTP];
    const int tid = threadIdx.x;
    const int lane = tid & 63;
    const int w = tid >> 6;
    const int chunk = blockIdx.x;
    const int c = chunk & 31;
    const int h = (chunk >> 5) & 15;
    const int b = chunk >> 9;
    const size_t rowbase = ((size_t)(b * T_ + c * L_)) * (3 * D_) + h * DH;
    const int fr = lane & 15;
    const int fg = lane >> 4;

    // Vt build: wave w covers t = w*16..w*16+15; quarter q covers V cols q*8..q*8+7
    {
        int t = w * 16 + (lane >> 2);
        int q = lane & 3;
        const unsigned short* vp = qkv + rowbase + (size_t)t * (3 * D_) + 2 * D_ + q * 8;
        bf16x8 v0 = *(const bf16x8*)vp;
        #pragma unroll
        for (int i = 0; i < 8; ++i)
            Vt[q * 8 + i][t] = (unsigned short)v0[i];
        if (q == 0) Vt[32][t] = 0x3F80;   // ones row
    }

    // Q fragment (phi pre-applied by producer)
    bf16x8 aq = *(const bf16x8*)(qkv + rowbase + (size_t)(w * 16 + fr) * (3 * D_) + fg * 8);
    // K fragments for col tiles n <= w (phi pre-applied)
    bf16x8 bk[4];
    #pragma unroll
    for (int n = 0; n < 4; ++n)
        if (n <= w)
            bk[n] = *(const bf16x8*)(qkv + rowbase + (size_t)(n * 16 + fr) * (3 * D_) + D_ + fg * 8);
    // prefix state fragments (rows e, incl. ks0 at e=32)
    bf16x8 bkv[3];
    #pragma unroll
    for (int n = 0; n < 3; ++n)
        bkv[n] = *(const bf16x8*)&cSt[(size_t)chunk * CSZ + (size_t)(n * 16 + fr) * 32 + fg * 8];

    // acc = Q @ KV0_ext  (output col 32 = den contribution q.ks0)
    f32x4 zero = (f32x4){0.f, 0.f, 0.f, 0.f};
    f32x4 acc[3];
    #pragma unroll
    for (int n = 0; n < 3; ++n)
        acc[n] = __builtin_amdgcn_mfma_f32_16x16x32_bf16(aq, bkv[n], zero, 0, 0, 0);

    // S tiles (lower triangle), masked, to per-wave LDS as bf16
    #pragma unroll
    for (int n = 0; n < 4; ++n) {
        if (n <= w) {
            f32x4 s = __builtin_amdgcn_mfma_f32_16x16x32_bf16(aq, bk[n], zero, 0, 0, 0);
            #pragma unroll
            for (int r = 0; r < 4; ++r) {
                unsigned short v = f2bf(s[r]);
                if (n == w && fr > fg * 4 + r) v = 0;
                Am[w][fg * 4 + r][n * 16 + fr] = v;
            }
        }
    }
    if ((w & 1) == 0) {
        int zc = (w + 1) * 16;
        *(uint2*)&Am[w][lane >> 2][zc + (lane & 3) * 4] = (uint2){0u, 0u};
    }
    __syncthreads();   // Vt is cross-wave

    // acc += A_masked @ V_ext
    #pragma unroll
    for (int ks = 0; ks < 2; ++ks) {
        if (ks <= (w >> 1)) {
            bf16x8 bv[3];
            #pragma unroll
            for (int n = 0; n < 3; ++n)
                bv[n] = *(const bf16x8*)&Vt[n * 16 + fr][fg * 8 + ks * 32];
            bf16x8 aa = *(const bf16x8*)&Am[w][fr][fg * 8 + ks * 32];
            #pragma unroll
            for (int n = 0; n < 3; ++n)
                acc[n] = __builtin_amdgcn_mfma_f32_16x16x32_bf16(aa, bv[n], acc[n], 0, 0, 0);
        }
    }

    // den broadcast (col 32 lives in lanes fr==0), divide, stage out via LDS
    float dn[4];
    #pragma unroll
    for (int r = 0; r < 4; ++r)
        dn[r] = __shfl(acc[2][r], lane & 48);
    #pragma unroll
    for (int r = 0; r < 4; ++r) {
        float inv = 1.0f / fmaxf(dn[r], 1e-6f);
        #pragma unroll
        for (int n = 0; n < 2; ++n)
            Am[w][fg * 4 + r][n * 16 + fr] = f2bf(acc[n][r] * inv);
    }
    // coalesced store: lane writes 16B (8 cols) of one row
    {
        int lrow = lane >> 2;
        int q = lane & 3;
        uint4 o = *(const uint4*)&Am[w][lrow][q * 8];
        size_t grow = (size_t)(b * T_ + c * L_ + w * 16 + lrow);
        *(uint4*)(attn + grow * D_ + h * DH + q * 8) = o;
    }
}

extern "C" void kernel_launch(void* const* d_in, const int* in_sizes, int n_in,
                              void* d_out, int out_size, void* d_ws, size_t ws_size,
                              hipStream_t stream) {
    const float* x     = (const float*)d_in[0];
    const float* w_qkv = (const float*)d_in[1];
    const float* w_out = (const float*)d_in[2];
    float* out = (float*)d_out;

    char* ws = (char*)d_ws;
    unsigned short* qkvb  = (unsigned short*)ws;                 // 12,582,912 B
    unsigned short* attnb = (unsigned short*)(ws + 12582912);    //  4,194,304 B
    float* cSf            = (float*)(ws + 16777216);             //  4,325,376 B  [1024][1056] f32
    unsigned short* cSt   = (unsigned short*)(ws + 21102592);    //  2,162,688 B  [1024][1056] bf16
    // total 23,265,280 B

    // 1) QKV projection + fused per-chunk local sums (1 block = 2 chunks, 128x96)
    gemm_qkv_cs<<<NC / 2, 256, 0, stream>>>(x, w_qkv, qkvb, cSf);

    // 2) exclusive prefix over chunks
    chunk_scan<<<132, 256, 0, stream>>>(cSf, cSt);

    // 3) per-chunk outputs -> bf16 attn
    chunk_out<<<NC, 256, 0, stream>>>(qkvb, cSt, attnb);

    // 4) output projection: bf16 attn (gload_lds) / fp32 w_out -> fp32 out
    gemm_nt<64, false, false><<<dim3(4096 / 64, 512 / 128), 256, 0, stream>>>(
        attnb, w_out, out, 512, 512);
}

// Round 18
// 45.701 us; speedup vs baseline: 1.1429x; 1.1429x over previous
//
#include <hip/hip_runtime.h>
#include <hip/hip_bf16.h>
#include <math.h>

#define B_ 2
#define T_ 2048
#define D_ 512
#define H_ 16
#define DH 32
#define L_ 64
#define C_ 32
#define NC 1024    // total chunks
#define VTP 72     // LDS row stride (ushorts) for chunk kernels
#define CSZ 1056   // floats per chunk state tile (33 rows x 32)

typedef __attribute__((ext_vector_type(8))) short bf16x8;
typedef __attribute__((ext_vector_type(4))) float f32x4;
typedef __attribute__((ext_vector_type(4))) unsigned short u16x4;

#define AS1 __attribute__((address_space(1)))
#define AS3 __attribute__((address_space(3)))

__device__ __forceinline__ float bf2f(unsigned short u) {
    union { float f; unsigned int i; } v; v.i = ((unsigned int)u) << 16; return v.f;
}
__device__ __forceinline__ unsigned short f2bf(float f) {
    union { float f; unsigned int u; } v; v.f = f;
    unsigned int u = v.u;
    unsigned int r = u + 0x7FFFu + ((u >> 16) & 1u);
    return (unsigned short)(r >> 16);
}
__device__ __forceinline__ unsigned short f2bf_rne(float f) {
    __hip_bfloat16 h = __float2bfloat16(f);
    union { __hip_bfloat16 h; unsigned short u; } v; v.h = h; return v.u;
}
__device__ __forceinline__ float phi_s(float f) {
    return f > 0.f ? f + 1.f : __expf(f);
}
__device__ __forceinline__ bf16x8 phi_frag(bf16x8 in) {
    bf16x8 r;
    #pragma unroll
    for (int i = 0; i < 8; ++i) {
        float f = bf2f((unsigned short)in[i]);
        r[i] = (short)f2bf(phi_s(f));
    }
    return r;
}
__device__ __forceinline__ void gload_lds16(const unsigned short* g, unsigned short* l) {
    __builtin_amdgcn_global_load_lds((const AS1 unsigned int*)g, (AS3 unsigned int*)l, 16, 0, 0);
}

// ---- gemm1 + fused chunk_sum: one block = one chunk (64 rows x one head's q|k|v).
// Computes qkv panel via MFMA (fp32 inputs reg-staged to bf16 LDS), writes qkvb,
// then reuses the fp32 accumulators to build phi(K)^T / V^T in LDS (unioned with
// dead staging buffers) and runs chunk_sum's 12 MFMAs -> cSf. Grid 1024 = 4/CU.
struct __align__(16) ShQ {
    union {
        struct { unsigned short As[2][64][32]; unsigned short Bs[2][96][32]; } g;  // 20480 B
        struct { unsigned short Kt[DH][VTP]; unsigned short Vt[48][VTP]; } s;      // 11520 B
    };
};

__global__ __launch_bounds__(256) void gemm_qkv_cs(const float* __restrict__ x,
                                                   const float* __restrict__ W,
                                                   unsigned short* __restrict__ qkvb,
                                                   float* __restrict__ cSf)
{
    __shared__ ShQ sh;
    const int tid = threadIdx.x;
    const int lane = tid & 63;
    const int w = tid >> 6;            // wave = 16-row strip
    const int chunk = blockIdx.x;
    const int c = chunk & 31;
    const int h = (chunk >> 5) & 15;
    const int b = chunk >> 9;
    const size_t R0 = (size_t)(b * T_ + c * L_);

    // staging map: thread -> (row sr 0..31, float col sc)
    const int sr = tid >> 3;
    const int sc = (tid & 7) * 4;
    const float* ax  = x + (R0 + sr) * 512 + sc;
    const float* wgq = W + ((size_t)(h * DH) + sr) * 512 + sc;
    const float* wgk = W + ((size_t)(D_ + h * DH) + sr) * 512 + sc;
    const float* wgv = W + ((size_t)(2 * D_ + h * DH) + sr) * 512 + sc;

    f32x4 aL[2], wL[3];
    auto load_stage = [&](int k0) {
        aL[0] = *(const f32x4*)(ax + k0);
        aL[1] = *(const f32x4*)(ax + k0 + (size_t)32 * 512);
        wL[0] = *(const f32x4*)(wgq + k0);
        wL[1] = *(const f32x4*)(wgk + k0);
        wL[2] = *(const f32x4*)(wgv + k0);
    };
    auto cvt4 = [](f32x4 v) {
        u16x4 o;
        o.x = f2bf_rne(v[0]); o.y = f2bf_rne(v[1]);
        o.z = f2bf_rne(v[2]); o.w = f2bf_rne(v[3]);
        return o;
    };
    auto write_stage = [&](int buf) {
        *(u16x4*)&sh.g.As[buf][sr][sc]      = cvt4(aL[0]);
        *(u16x4*)&sh.g.As[buf][sr + 32][sc] = cvt4(aL[1]);
        *(u16x4*)&sh.g.Bs[buf][sr][sc]      = cvt4(wL[0]);
        *(u16x4*)&sh.g.Bs[buf][sr + 32][sc] = cvt4(wL[1]);
        *(u16x4*)&sh.g.Bs[buf][sr + 64][sc] = cvt4(wL[2]);
    };

    f32x4 acc[6];
    #pragma unroll
    for (int n = 0; n < 6; ++n) acc[n] = (f32x4){0.f, 0.f, 0.f, 0.f};

    const int rr = lane & 15;
    const int fg = lane >> 4;
    const int kb = fg * 8;

    load_stage(0);
    write_stage(0);
    __syncthreads();
    int cur = 0;
    for (int k0 = 0; k0 < 512; k0 += 32) {
        const bool more = k0 + 32 < 512;
        if (more) load_stage(k0 + 32);
        bf16x8 af = *(const bf16x8*)&sh.g.As[cur][w * 16 + rr][kb];
        bf16x8 bfr[6];
        #pragma unroll
        for (int n = 0; n < 6; ++n)
            bfr[n] = *(const bf16x8*)&sh.g.Bs[cur][n * 16 + rr][kb];
        #pragma unroll
        for (int n = 0; n < 6; ++n)
            acc[n] = __builtin_amdgcn_mfma_f32_16x16x32_bf16(af, bfr[n], acc[n], 0, 0, 0);
        if (more) write_stage(cur ^ 1);
        __syncthreads();
        cur ^= 1;
    }

    // ---- epilogue A: write qkv panel to global (C/D map: col=rr, row=fg*4+j)
    {
        const int colbase[6] = { h * DH, h * DH + 16,
                                 D_ + h * DH, D_ + h * DH + 16,
                                 2 * D_ + h * DH, 2 * D_ + h * DH + 16 };
        #pragma unroll
        for (int n = 0; n < 6; ++n)
            #pragma unroll
            for (int j = 0; j < 4; ++j) {
                size_t row = R0 + w * 16 + fg * 4 + j;
                qkvb[row * 1536 + colbase[n] + rr] = f2bf(acc[n][j]);
            }
    }

    // ---- epilogue B: transpose phi(K), V into LDS (staging buffers dead after
    // the K-loop's final barrier), then chunk_sum's MFMAs on waves 0..2.
    #pragma unroll
    for (int n = 2; n < 4; ++n)
        #pragma unroll
        for (int j = 0; j < 4; ++j)
            sh.s.Kt[(n - 2) * 16 + rr][w * 16 + fg * 4 + j] = f2bf(phi_s(acc[n][j]));
    #pragma unroll
    for (int n = 4; n < 6; ++n)
        #pragma unroll
        for (int j = 0; j < 4; ++j)
            sh.s.Vt[(n - 4) * 16 + rr][w * 16 + fg * 4 + j] = f2bf(acc[n][j]);
    if (rr == 0) {
        #pragma unroll
        for (int j = 0; j < 4; ++j)
            sh.s.Vt[32][w * 16 + fg * 4 + j] = 0x3F80;   // ones row
    }
    __syncthreads();

    if (w < 3) {    // wave m computes ST rows m*16..m*16+15 (m=2: only e=32 used)
        f32x4 a2[2];
        a2[0] = (f32x4){0.f, 0.f, 0.f, 0.f};
        a2[1] = (f32x4){0.f, 0.f, 0.f, 0.f};
        #pragma unroll
        for (int ks = 0; ks < 2; ++ks) {
            int toff = fg * 8 + ks * 32;
            bf16x8 av = *(const bf16x8*)&sh.s.Vt[w * 16 + rr][toff];
            bf16x8 bkk[2];
            #pragma unroll
            for (int n = 0; n < 2; ++n)
                bkk[n] = *(const bf16x8*)&sh.s.Kt[n * 16 + rr][toff];
            #pragma unroll
            for (int n = 0; n < 2; ++n)
                a2[n] = __builtin_amdgcn_mfma_f32_16x16x32_bf16(av, bkk[n], a2[n], 0, 0, 0);
        }
        float* outp = cSf + (size_t)chunk * CSZ;
        if (w < 2) {
            #pragma unroll
            for (int n = 0; n < 2; ++n)
                #pragma unroll
                for (int r = 0; r < 4; ++r)
                    outp[(w * 16 + fg * 4 + r) * 32 + n * 16 + rr] = a2[n][r];
        } else if (fg == 0) {
            #pragma unroll
            for (int n = 0; n < 2; ++n)
                outp[32 * 32 + n * 16 + rr] = a2[n][0];
        }
    }
}

// ---- gemm2: out = attn @ w_out^T. A bf16 via global_load_lds; W fp32 reg-staged.
// BN-parameterized: BN=64 -> (64,8)=512 blocks = 2 blocks/CU for latency hiding.
template<int BM, int BN, bool AF32, bool OUT_BF16>
__global__ __launch_bounds__(256) void gemm_nt(const void* __restrict__ Aptr,
                                               const float* __restrict__ Wf,
                                               void* __restrict__ Cout,
                                               int N, int K)
{
    constexpr int MF = BM / 32;        // m-fragments per wave
    constexpr int NF = BN / 32;        // n-fragments per wave
    constexpr int AF4 = BM / 32;       // float4 loads per lane for fp32 A staging
    constexpr int WL = BN / 32;        // W float4 loads per lane
    __shared__ unsigned short As[2][BM][32];
    __shared__ unsigned short Bs[2][BN][32];
    const int tid = threadIdx.x;
    const int lane = tid & 63;
    const int wave = tid >> 6;
    const int wr = wave >> 1;
    const int wc = wave & 1;
    const size_t bm = (size_t)blockIdx.x * BM;
    const size_t bn = (size_t)blockIdx.y * BN;

    const int r8 = lane >> 3;          // 0..7 (f32 staging row-in-group)
    const int c4 = (lane & 7) * 4;     // f32 staging col (floats)
    const int lrow = lane >> 2;        // bf16 gload row
    const int lcol = (lane & 3) * 8;   // bf16 gload col

    const float* agf = nullptr;
    const unsigned short* agb = nullptr;
    if constexpr (AF32) agf = (const float*)Aptr + (bm + wave * (BM / 4) + r8) * (size_t)K + c4;
    else                agb = (const unsigned short*)Aptr + (bm + wave * (BM / 4) + lrow) * (size_t)K + lcol;
    const float* wgf = Wf + (bn + wave * (BN / 4) + r8) * (size_t)K + c4;

    f32x4 aL[AF4];
    f32x4 wL[WL];

    auto load_stage = [&](int buf, int k0) {
        if constexpr (AF32) {
            #pragma unroll
            for (int i = 0; i < AF4; ++i)
                aL[i] = *(const f32x4*)(agf + k0 + (size_t)(i * 8) * K);
        } else {
            gload_lds16(agb + k0, &As[buf][wave * (BM / 4)][0]);
            if constexpr (BM / 4 == 32)
                gload_lds16(agb + (size_t)16 * K + k0, &As[buf][wave * (BM / 4) + 16][0]);
        }
        #pragma unroll
        for (int i = 0; i < WL; ++i)
            wL[i] = *(const f32x4*)(wgf + k0 + (size_t)(i * 8) * K);
    };
    auto write_stage = [&](int buf) {
        if constexpr (AF32) {
            #pragma unroll
            for (int i = 0; i < AF4; ++i) {
                u16x4 o;
                o.x = f2bf_rne(aL[i][0]); o.y = f2bf_rne(aL[i][1]);
                o.z = f2bf_rne(aL[i][2]); o.w = f2bf_rne(aL[i][3]);
                *(u16x4*)&As[buf][wave * (BM / 4) + r8 + i * 8][c4] = o;
            }
        }
        #pragma unroll
        for (int i = 0; i < WL; ++i) {
            u16x4 o;
            o.x = f2bf_rne(wL[i][0]); o.y = f2bf_rne(wL[i][1]);
            o.z = f2bf_rne(wL[i][2]); o.w = f2bf_rne(wL[i][3]);
            *(u16x4*)&Bs[buf][wave * (BN / 4) + r8 + i * 8][c4] = o;
        }
    };

    f32x4 acc[MF][NF];
    #pragma unroll
    for (int m = 0; m < MF; ++m)
        #pragma unroll
        for (int n = 0; n < NF; ++n)
            acc[m][n] = (f32x4){0.f, 0.f, 0.f, 0.f};

    const int rr = lane & 15;
    const int kb = (lane >> 4) * 8;

    load_stage(0, 0);
    write_stage(0);
    __syncthreads();
    int cur = 0;
    for (int k0 = 0; k0 < K; k0 += 32) {
        const bool more = k0 + 32 < K;
        if (more) load_stage(cur ^ 1, k0 + 32);
        bf16x8 af[MF], bfr[NF];
        #pragma unroll
        for (int m = 0; m < MF; ++m)
            af[m] = *(const bf16x8*)&As[cur][wr * (BM / 2) + m * 16 + rr][kb];
        #pragma unroll
        for (int n = 0; n < NF; ++n)
            bfr[n] = *(const bf16x8*)&Bs[cur][wc * (BN / 2) + n * 16 + rr][kb];
        #pragma unroll
        for (int m = 0; m < MF; ++m)
            #pragma unroll
            for (int n = 0; n < NF; ++n)
                acc[m][n] = __builtin_amdgcn_mfma_f32_16x16x32_bf16(af[m], bfr[n], acc[m][n], 0, 0, 0);
        if (more) write_stage(cur ^ 1);
        __syncthreads();
        cur ^= 1;
    }

    const int cr = (lane >> 4) * 4;
    const int cc = lane & 15;
    #pragma unroll
    for (int m = 0; m < MF; ++m)
        #pragma unroll
        for (int n = 0; n < NF; ++n)
            #pragma unroll
            for (int j = 0; j < 4; ++j) {
                size_t row = bm + wr * (BM / 2) + m * 16 + cr + j;
                size_t col = bn + wc * (BN / 2) + n * 16 + cc;
                float v = acc[m][n][j];
                if (OUT_BF16) ((unsigned short*)Cout)[row * N + col] = f2bf(v);
                else          ((float*)Cout)[row * N + col] = v;
            }
}

// Exclusive prefix over chunks; emit bf16 state cSt[chunk][e*32+d].
__global__ __launch_bounds__(256) void chunk_scan(const float* __restrict__ cSf,
                                                  unsigned short* __restrict__ cSt)
{
    int idx = blockIdx.x * 256 + threadIdx.x;     // 32*1056 = 33792 exactly
    int bh = idx / CSZ;
    int r  = idx % CSZ;
    const float* src = cSf + (size_t)bh * C_ * CSZ + r;
    unsigned short* dst = cSt + (size_t)bh * C_ * CSZ + r;
    float v[C_];
    #pragma unroll
    for (int c = 0; c < C_; ++c) v[c] = src[(size_t)c * CSZ];
    float acc = 0.f;
    #pragma unroll
    for (int c = 0; c < C_; ++c) {
        dst[(size_t)c * CSZ] = f2bf(acc);
        acc += v[c];
    }
}

// Per-chunk output via MFMA. ONE chunk per block; 4 waves, wave w owns m-tile w.
__global__ __launch_bounds__(256) void chunk_out(const unsigned short* __restrict__ qkv,
                                                 const unsigned short* __restrict__ cSt,
                                                 unsigned short* __restrict__ attn)
{
    __shared__ unsigned short Vt[48][VTP];
    __shared__ unsigned short Am[4][16][VTP];
    const int tid = threadIdx.x;
    const int lane = tid & 63;
    const int w = tid >> 6;
    const int chunk = blockIdx.x;
    const int c = chunk & 31;
    const int h = (chunk >> 5) & 15;
    const int b = chunk >> 9;
    const size_t rowbase = ((size_t)(b * T_ + c * L_)) * (3 * D_) + h * DH;
    const int fr = lane & 15;
    const int fg = lane >> 4;

    {
        int t = w * 16 + (lane >> 2);
        int q = lane & 3;
        const unsigned short* vp = qkv + rowbase + (size_t)t * (3 * D_) + 2 * D_ + q * 8;
        bf16x8 v0 = *(const bf16x8*)vp;
        #pragma unroll
        for (int i = 0; i < 8; ++i)
            Vt[q * 8 + i][t] = (unsigned short)v0[i];
        if (q == 0) Vt[32][t] = 0x3F80;
    }

    bf16x8 aq;
    {
        const unsigned short* qp = qkv + rowbase + (size_t)(w * 16 + fr) * (3 * D_) + fg * 8;
        aq = phi_frag(*(const bf16x8*)qp);
    }
    bf16x8 bk[4];
    #pragma unroll
    for (int n = 0; n < 4; ++n) {
        if (n <= w) {
            const unsigned short* kp = qkv + rowbase + (size_t)(n * 16 + fr) * (3 * D_) + D_ + fg * 8;
            bk[n] = phi_frag(*(const bf16x8*)kp);
        }
    }
    bf16x8 bkv[3];
    #pragma unroll
    for (int n = 0; n < 3; ++n)
        bkv[n] = *(const bf16x8*)&cSt[(size_t)chunk * CSZ + (size_t)(n * 16 + fr) * 32 + fg * 8];

    f32x4 zero = (f32x4){0.f, 0.f, 0.f, 0.f};
    f32x4 acc[3];
    #pragma unroll
    for (int n = 0; n < 3; ++n)
        acc[n] = __builtin_amdgcn_mfma_f32_16x16x32_bf16(aq, bkv[n], zero, 0, 0, 0);

    #pragma unroll
    for (int n = 0; n < 4; ++n) {
        if (n <= w) {
            f32x4 s = __builtin_amdgcn_mfma_f32_16x16x32_bf16(aq, bk[n], zero, 0, 0, 0);
            #pragma unroll
            for (int r = 0; r < 4; ++r) {
                unsigned short v = f2bf(s[r]);
                if (n == w && fr > fg * 4 + r) v = 0;
                Am[w][fg * 4 + r][n * 16 + fr] = v;
            }
        }
    }
    if ((w & 1) == 0) {
        int zc = (w + 1) * 16;
        *(uint2*)&Am[w][lane >> 2][zc + (lane & 3) * 4] = (uint2){0u, 0u};
    }
    __syncthreads();

    #pragma unroll
    for (int ks = 0; ks < 2; ++ks) {
        if (ks <= (w >> 1)) {
            bf16x8 bv[3];
            #pragma unroll
            for (int n = 0; n < 3; ++n)
                bv[n] = *(const bf16x8*)&Vt[n * 16 + fr][fg * 8 + ks * 32];
            bf16x8 aa = *(const bf16x8*)&Am[w][fr][fg * 8 + ks * 32];
            #pragma unroll
            for (int n = 0; n < 3; ++n)
                acc[n] = __builtin_amdgcn_mfma_f32_16x16x32_bf16(aa, bv[n], acc[n], 0, 0, 0);
        }
    }

    float dn[4];
    #pragma unroll
    for (int r = 0; r < 4; ++r)
        dn[r] = __shfl(acc[2][r], lane & 48);
    #pragma unroll
    for (int r = 0; r < 4; ++r) {
        float inv = 1.0f / fmaxf(dn[r], 1e-6f);
        #pragma unroll
        for (int n = 0; n < 2; ++n)
            Am[w][fg * 4 + r][n * 16 + fr] = f2bf(acc[n][r] * inv);
    }
    {
        int lrow = lane >> 2;
        int q = lane & 3;
        uint4 o = *(const uint4*)&Am[w][lrow][q * 8];
        size_t grow = (size_t)(b * T_ + c * L_ + w * 16 + lrow);
        *(uint4*)(attn + grow * D_ + h * DH + q * 8) = o;
    }
}

extern "C" void kernel_launch(void* const* d_in, const int* in_sizes, int n_in,
                              void* d_out, int out_size, void* d_ws, size_t ws_size,
                              hipStream_t stream) {
    const float* x     = (const float*)d_in[0];
    const float* w_qkv = (const float*)d_in[1];
    const float* w_out = (const float*)d_in[2];
    float* out = (float*)d_out;

    char* ws = (char*)d_ws;
    unsigned short* qkvb  = (unsigned short*)ws;                 // 12,582,912 B
    unsigned short* attnb = (unsigned short*)(ws + 12582912);    //  4,194,304 B
    float* cSf            = (float*)(ws + 16777216);             //  4,325,376 B  [1024][1056] f32
    unsigned short* cSt   = (unsigned short*)(ws + 21102592);    //  2,162,688 B  [1024][1056] bf16
    // total 23,265,280 B

    // 1) QKV projection + fused per-chunk local sums (1 block = 1 chunk)
    gemm_qkv_cs<<<NC, 256, 0, stream>>>(x, w_qkv, qkvb, cSf);

    // 2) exclusive prefix over chunks
    chunk_scan<<<132, 256, 0, stream>>>(cSf, cSt);

    // 3) per-chunk outputs -> bf16 attn
    chunk_out<<<NC, 256, 0, stream>>>(qkvb, cSt, attnb);

    // 4) output projection: 64x64 tiles -> 512 blocks = 2/CU (was 256 = 1/CU)
    gemm_nt<64, 64, false, false><<<dim3(4096 / 64, 512 / 64), 256, 0, stream>>>(
        attnb, w_out, out, 512, 512);
}

// Round 19
// 44.368 us; speedup vs baseline: 1.1773x; 1.0300x over previous
//
#include <hip/hip_runtime.h>
#include <hip/hip_bf16.h>
#include <math.h>

#define B_ 2
#define T_ 2048
#define D_ 512
#define H_ 16
#define DH 32
#define L_ 64
#define C_ 32
#define NC 1024    // total chunks
#define VTP 72     // LDS row stride (ushorts) for chunk kernels
#define CSZ 1056   // floats per chunk state tile (33 rows x 32)

typedef __attribute__((ext_vector_type(8))) short bf16x8;
typedef __attribute__((ext_vector_type(4))) float f32x4;
typedef __attribute__((ext_vector_type(4))) unsigned short u16x4;

#define AS1 __attribute__((address_space(1)))
#define AS3 __attribute__((address_space(3)))

__device__ __forceinline__ float bf2f(unsigned short u) {
    union { float f; unsigned int i; } v; v.i = ((unsigned int)u) << 16; return v.f;
}
__device__ __forceinline__ unsigned short f2bf(float f) {
    union { float f; unsigned int u; } v; v.f = f;
    unsigned int u = v.u;
    unsigned int r = u + 0x7FFFu + ((u >> 16) & 1u);
    return (unsigned short)(r >> 16);
}
__device__ __forceinline__ unsigned short f2bf_rne(float f) {
    __hip_bfloat16 h = __float2bfloat16(f);
    union { __hip_bfloat16 h; unsigned short u; } v; v.h = h; return v.u;
}
__device__ __forceinline__ float phi_s(float f) {
    return f > 0.f ? f + 1.f : __expf(f);
}
__device__ __forceinline__ void gload_lds16(const unsigned short* g, unsigned short* l) {
    __builtin_amdgcn_global_load_lds((const AS1 unsigned int*)g, (AS3 unsigned int*)l, 16, 0, 0);
}

// ---- gemm1 + fused chunk_sum: one block = one chunk (64 rows x one head's q|k|v).
// qkvb receives phi(q), phi(k), raw v (qkvb's ONLY consumer is chunk_out, which
// needs exactly these). Epilogue B reuses accumulators for chunk_sum -> cSf.
struct __align__(16) ShQ {
    union {
        struct { unsigned short As[2][64][32]; unsigned short Bs[2][96][32]; } g;  // 20480 B
        struct { unsigned short Kt[DH][VTP]; unsigned short Vt[48][VTP]; } s;      // 11520 B
    };
};

__global__ __launch_bounds__(256) void gemm_qkv_cs(const float* __restrict__ x,
                                                   const float* __restrict__ W,
                                                   unsigned short* __restrict__ qkvb,
                                                   float* __restrict__ cSf)
{
    __shared__ ShQ sh;
    const int tid = threadIdx.x;
    const int lane = tid & 63;
    const int w = tid >> 6;            // wave = 16-row strip
    const int chunk = blockIdx.x;
    const int c = chunk & 31;
    const int h = (chunk >> 5) & 15;
    const int b = chunk >> 9;
    const size_t R0 = (size_t)(b * T_ + c * L_);

    // staging map: thread -> (row sr 0..31, float col sc)
    const int sr = tid >> 3;
    const int sc = (tid & 7) * 4;
    const float* ax  = x + (R0 + sr) * 512 + sc;
    const float* wgq = W + ((size_t)(h * DH) + sr) * 512 + sc;
    const float* wgk = W + ((size_t)(D_ + h * DH) + sr) * 512 + sc;
    const float* wgv = W + ((size_t)(2 * D_ + h * DH) + sr) * 512 + sc;

    f32x4 aL[2], wL[3];
    auto load_stage = [&](int k0) {
        aL[0] = *(const f32x4*)(ax + k0);
        aL[1] = *(const f32x4*)(ax + k0 + (size_t)32 * 512);
        wL[0] = *(const f32x4*)(wgq + k0);
        wL[1] = *(const f32x4*)(wgk + k0);
        wL[2] = *(const f32x4*)(wgv + k0);
    };
    auto cvt4 = [](f32x4 v) {
        u16x4 o;
        o.x = f2bf_rne(v[0]); o.y = f2bf_rne(v[1]);
        o.z = f2bf_rne(v[2]); o.w = f2bf_rne(v[3]);
        return o;
    };
    auto write_stage = [&](int buf) {
        *(u16x4*)&sh.g.As[buf][sr][sc]      = cvt4(aL[0]);
        *(u16x4*)&sh.g.As[buf][sr + 32][sc] = cvt4(aL[1]);
        *(u16x4*)&sh.g.Bs[buf][sr][sc]      = cvt4(wL[0]);
        *(u16x4*)&sh.g.Bs[buf][sr + 32][sc] = cvt4(wL[1]);
        *(u16x4*)&sh.g.Bs[buf][sr + 64][sc] = cvt4(wL[2]);
    };

    f32x4 acc[6];
    #pragma unroll
    for (int n = 0; n < 6; ++n) acc[n] = (f32x4){0.f, 0.f, 0.f, 0.f};

    const int rr = lane & 15;
    const int fg = lane >> 4;
    const int kb = fg * 8;

    load_stage(0);
    write_stage(0);
    __syncthreads();
    int cur = 0;
    for (int k0 = 0; k0 < 512; k0 += 32) {
        const bool more = k0 + 32 < 512;
        if (more) load_stage(k0 + 32);
        bf16x8 af = *(const bf16x8*)&sh.g.As[cur][w * 16 + rr][kb];
        bf16x8 bfr[6];
        #pragma unroll
        for (int n = 0; n < 6; ++n)
            bfr[n] = *(const bf16x8*)&sh.g.Bs[cur][n * 16 + rr][kb];
        #pragma unroll
        for (int n = 0; n < 6; ++n)
            acc[n] = __builtin_amdgcn_mfma_f32_16x16x32_bf16(af, bfr[n], acc[n], 0, 0, 0);
        if (more) write_stage(cur ^ 1);
        __syncthreads();
        cur ^= 1;
    }

    // ---- epilogue A: write qkv panel to global; q,k get phi PRE-applied
    {
        const int colbase[6] = { h * DH, h * DH + 16,
                                 D_ + h * DH, D_ + h * DH + 16,
                                 2 * D_ + h * DH, 2 * D_ + h * DH + 16 };
        #pragma unroll
        for (int n = 0; n < 6; ++n)
            #pragma unroll
            for (int j = 0; j < 4; ++j) {
                size_t row = R0 + w * 16 + fg * 4 + j;
                float v = (n < 4) ? phi_s(acc[n][j]) : acc[n][j];
                qkvb[row * 1536 + colbase[n] + rr] = f2bf(v);
            }
    }

    // ---- epilogue B: transpose phi(K), V into LDS (staging buffers dead after
    // the K-loop's final barrier), then chunk_sum's MFMAs on waves 0..2.
    #pragma unroll
    for (int n = 2; n < 4; ++n)
        #pragma unroll
        for (int j = 0; j < 4; ++j)
            sh.s.Kt[(n - 2) * 16 + rr][w * 16 + fg * 4 + j] = f2bf(phi_s(acc[n][j]));
    #pragma unroll
    for (int n = 4; n < 6; ++n)
        #pragma unroll
        for (int j = 0; j < 4; ++j)
            sh.s.Vt[(n - 4) * 16 + rr][w * 16 + fg * 4 + j] = f2bf(acc[n][j]);
    if (rr == 0) {
        #pragma unroll
        for (int j = 0; j < 4; ++j)
            sh.s.Vt[32][w * 16 + fg * 4 + j] = 0x3F80;   // ones row
    }
    __syncthreads();

    if (w < 3) {    // wave m computes ST rows m*16..m*16+15 (m=2: only e=32 used)
        f32x4 a2[2];
        a2[0] = (f32x4){0.f, 0.f, 0.f, 0.f};
        a2[1] = (f32x4){0.f, 0.f, 0.f, 0.f};
        #pragma unroll
        for (int ks = 0; ks < 2; ++ks) {
            int toff = fg * 8 + ks * 32;
            bf16x8 av = *(const bf16x8*)&sh.s.Vt[w * 16 + rr][toff];
            bf16x8 bkk[2];
            #pragma unroll
            for (int n = 0; n < 2; ++n)
                bkk[n] = *(const bf16x8*)&sh.s.Kt[n * 16 + rr][toff];
            #pragma unroll
            for (int n = 0; n < 2; ++n)
                a2[n] = __builtin_amdgcn_mfma_f32_16x16x32_bf16(av, bkk[n], a2[n], 0, 0, 0);
        }
        float* outp = cSf + (size_t)chunk * CSZ;
        if (w < 2) {
            #pragma unroll
            for (int n = 0; n < 2; ++n)
                #pragma unroll
                for (int r = 0; r < 4; ++r)
                    outp[(w * 16 + fg * 4 + r) * 32 + n * 16 + rr] = a2[n][r];
        } else if (fg == 0) {
            #pragma unroll
            for (int n = 0; n < 2; ++n)
                outp[32 * 32 + n * 16 + rr] = a2[n][0];
        }
    }
}

// ---- gemm2: out = attn @ w_out^T. A bf16 via global_load_lds; W fp32 reg-staged.
template<int BM, int BN, bool AF32, bool OUT_BF16>
__global__ __launch_bounds__(256) void gemm_nt(const void* __restrict__ Aptr,
                                               const float* __restrict__ Wf,
                                               void* __restrict__ Cout,
                                               int N, int K)
{
    constexpr int MF = BM / 32;
    constexpr int NF = BN / 32;
    constexpr int AF4 = BM / 32;
    constexpr int WL = BN / 32;
    __shared__ unsigned short As[2][BM][32];
    __shared__ unsigned short Bs[2][BN][32];
    const int tid = threadIdx.x;
    const int lane = tid & 63;
    const int wave = tid >> 6;
    const int wr = wave >> 1;
    const int wc = wave & 1;
    const size_t bm = (size_t)blockIdx.x * BM;
    const size_t bn = (size_t)blockIdx.y * BN;

    const int r8 = lane >> 3;
    const int c4 = (lane & 7) * 4;
    const int lrow = lane >> 2;
    const int lcol = (lane & 3) * 8;

    const float* agf = nullptr;
    const unsigned short* agb = nullptr;
    if constexpr (AF32) agf = (const float*)Aptr + (bm + wave * (BM / 4) + r8) * (size_t)K + c4;
    else                agb = (const unsigned short*)Aptr + (bm + wave * (BM / 4) + lrow) * (size_t)K + lcol;
    const float* wgf = Wf + (bn + wave * (BN / 4) + r8) * (size_t)K + c4;

    f32x4 aL[AF4];
    f32x4 wL[WL];

    auto load_stage = [&](int buf, int k0) {
        if constexpr (AF32) {
            #pragma unroll
            for (int i = 0; i < AF4; ++i)
                aL[i] = *(const f32x4*)(agf + k0 + (size_t)(i * 8) * K);
        } else {
            gload_lds16(agb + k0, &As[buf][wave * (BM / 4)][0]);
            if constexpr (BM / 4 == 32)
                gload_lds16(agb + (size_t)16 * K + k0, &As[buf][wave * (BM / 4) + 16][0]);
        }
        #pragma unroll
        for (int i = 0; i < WL; ++i)
            wL[i] = *(const f32x4*)(wgf + k0 + (size_t)(i * 8) * K);
    };
    auto write_stage = [&](int buf) {
        if constexpr (AF32) {
            #pragma unroll
            for (int i = 0; i < AF4; ++i) {
                u16x4 o;
                o.x = f2bf_rne(aL[i][0]); o.y = f2bf_rne(aL[i][1]);
                o.z = f2bf_rne(aL[i][2]); o.w = f2bf_rne(aL[i][3]);
                *(u16x4*)&As[buf][wave * (BM / 4) + r8 + i * 8][c4] = o;
            }
        }
        #pragma unroll
        for (int i = 0; i < WL; ++i) {
            u16x4 o;
            o.x = f2bf_rne(wL[i][0]); o.y = f2bf_rne(wL[i][1]);
            o.z = f2bf_rne(wL[i][2]); o.w = f2bf_rne(wL[i][3]);
            *(u16x4*)&Bs[buf][wave * (BN / 4) + r8 + i * 8][c4] = o;
        }
    };

    f32x4 acc[MF][NF];
    #pragma unroll
    for (int m = 0; m < MF; ++m)
        #pragma unroll
        for (int n = 0; n < NF; ++n)
            acc[m][n] = (f32x4){0.f, 0.f, 0.f, 0.f};

    const int rr = lane & 15;
    const int kb = (lane >> 4) * 8;

    load_stage(0, 0);
    write_stage(0);
    __syncthreads();
    int cur = 0;
    for (int k0 = 0; k0 < K; k0 += 32) {
        const bool more = k0 + 32 < K;
        if (more) load_stage(cur ^ 1, k0 + 32);
        bf16x8 af[MF], bfr[NF];
        #pragma unroll
        for (int m = 0; m < MF; ++m)
            af[m] = *(const bf16x8*)&As[cur][wr * (BM / 2) + m * 16 + rr][kb];
        #pragma unroll
        for (int n = 0; n < NF; ++n)
            bfr[n] = *(const bf16x8*)&Bs[cur][wc * (BN / 2) + n * 16 + rr][kb];
        #pragma unroll
        for (int m = 0; m < MF; ++m)
            #pragma unroll
            for (int n = 0; n < NF; ++n)
                acc[m][n] = __builtin_amdgcn_mfma_f32_16x16x32_bf16(af[m], bfr[n], acc[m][n], 0, 0, 0);
        if (more) write_stage(cur ^ 1);
        __syncthreads();
        cur ^= 1;
    }

    const int cr = (lane >> 4) * 4;
    const int cc = lane & 15;
    #pragma unroll
    for (int m = 0; m < MF; ++m)
        #pragma unroll
        for (int n = 0; n < NF; ++n)
            #pragma unroll
            for (int j = 0; j < 4; ++j) {
                size_t row = bm + wr * (BM / 2) + m * 16 + cr + j;
                size_t col = bn + wc * (BN / 2) + n * 16 + cc;
                float v = acc[m][n][j];
                if (OUT_BF16) ((unsigned short*)Cout)[row * N + col] = f2bf(v);
                else          ((float*)Cout)[row * N + col] = v;
            }
}

// Exclusive prefix over chunks; emit bf16 state cSt[chunk][e*32+d].
__global__ __launch_bounds__(256) void chunk_scan(const float* __restrict__ cSf,
                                                  unsigned short* __restrict__ cSt)
{
    int idx = blockIdx.x * 256 + threadIdx.x;     // 32*1056 = 33792 exactly
    int bh = idx / CSZ;
    int r  = idx % CSZ;
    const float* src = cSf + (size_t)bh * C_ * CSZ + r;
    unsigned short* dst = cSt + (size_t)bh * C_ * CSZ + r;
    float v[C_];
    #pragma unroll
    for (int c = 0; c < C_; ++c) v[c] = src[(size_t)c * CSZ];
    float acc = 0.f;
    #pragma unroll
    for (int c = 0; c < C_; ++c) {
        dst[(size_t)c * CSZ] = f2bf(acc);
        acc += v[c];
    }
}

// Per-chunk output via MFMA. ONE chunk per block; 4 waves, wave w owns m-tile w.
// qkv holds phi(q)/phi(k) pre-applied -> plain fragment loads (no exp on this path).
__global__ __launch_bounds__(256) void chunk_out(const unsigned short* __restrict__ qkv,
                                                 const unsigned short* __restrict__ cSt,
                                                 unsigned short* __restrict__ attn)
{
    __shared__ unsigned short Vt[48][VTP];
    __shared__ unsigned short Am[4][16][VTP];
    const int tid = threadIdx.x;
    const int lane = tid & 63;
    const int w = tid >> 6;
    const int chunk = blockIdx.x;
    const int c = chunk & 31;
    const int h = (chunk >> 5) & 15;
    const int b = chunk >> 9;
    const size_t rowbase = ((size_t)(b * T_ + c * L_)) * (3 * D_) + h * DH;
    const int fr = lane & 15;
    const int fg = lane >> 4;

    {
        int t = w * 16 + (lane >> 2);
        int q = lane & 3;
        const unsigned short* vp = qkv + rowbase + (size_t)t * (3 * D_) + 2 * D_ + q * 8;
        bf16x8 v0 = *(const bf16x8*)vp;
        #pragma unroll
        for (int i = 0; i < 8; ++i)
            Vt[q * 8 + i][t] = (unsigned short)v0[i];
        if (q == 0) Vt[32][t] = 0x3F80;
    }

    // Q fragment (phi pre-applied by producer)
    bf16x8 aq = *(const bf16x8*)(qkv + rowbase + (size_t)(w * 16 + fr) * (3 * D_) + fg * 8);
    // K fragments for col tiles n <= w (phi pre-applied)
    bf16x8 bk[4];
    #pragma unroll
    for (int n = 0; n < 4; ++n)
        if (n <= w)
            bk[n] = *(const bf16x8*)(qkv + rowbase + (size_t)(n * 16 + fr) * (3 * D_) + D_ + fg * 8);
    bf16x8 bkv[3];
    #pragma unroll
    for (int n = 0; n < 3; ++n)
        bkv[n] = *(const bf16x8*)&cSt[(size_t)chunk * CSZ + (size_t)(n * 16 + fr) * 32 + fg * 8];

    f32x4 zero = (f32x4){0.f, 0.f, 0.f, 0.f};
    f32x4 acc[3];
    #pragma unroll
    for (int n = 0; n < 3; ++n)
        acc[n] = __builtin_amdgcn_mfma_f32_16x16x32_bf16(aq, bkv[n], zero, 0, 0, 0);

    #pragma unroll
    for (int n = 0; n < 4; ++n) {
        if (n <= w) {
            f32x4 s = __builtin_amdgcn_mfma_f32_16x16x32_bf16(aq, bk[n], zero, 0, 0, 0);
            #pragma unroll
            for (int r = 0; r < 4; ++r) {
                unsigned short v = f2bf(s[r]);
                if (n == w && fr > fg * 4 + r) v = 0;
                Am[w][fg * 4 + r][n * 16 + fr] = v;
            }
        }
    }
    if ((w & 1) == 0) {
        int zc = (w + 1) * 16;
        *(uint2*)&Am[w][lane >> 2][zc + (lane & 3) * 4] = (uint2){0u, 0u};
    }
    __syncthreads();

    #pragma unroll
    for (int ks = 0; ks < 2; ++ks) {
        if (ks <= (w >> 1)) {
            bf16x8 bv[3];
            #pragma unroll
            for (int n = 0; n < 3; ++n)
                bv[n] = *(const bf16x8*)&Vt[n * 16 + fr][fg * 8 + ks * 32];
            bf16x8 aa = *(const bf16x8*)&Am[w][fr][fg * 8 + ks * 32];
            #pragma unroll
            for (int n = 0; n < 3; ++n)
                acc[n] = __builtin_amdgcn_mfma_f32_16x16x32_bf16(aa, bv[n], acc[n], 0, 0, 0);
        }
    }

    float dn[4];
    #pragma unroll
    for (int r = 0; r < 4; ++r)
        dn[r] = __shfl(acc[2][r], lane & 48);
    #pragma unroll
    for (int r = 0; r < 4; ++r) {
        float inv = 1.0f / fmaxf(dn[r], 1e-6f);
        #pragma unroll
        for (int n = 0; n < 2; ++n)
            Am[w][fg * 4 + r][n * 16 + fr] = f2bf(acc[n][r] * inv);
    }
    {
        int lrow = lane >> 2;
        int q = lane & 3;
        uint4 o = *(const uint4*)&Am[w][lrow][q * 8];
        size_t grow = (size_t)(b * T_ + c * L_ + w * 16 + lrow);
        *(uint4*)(attn + grow * D_ + h * DH + q * 8) = o;
    }
}

extern "C" void kernel_launch(void* const* d_in, const int* in_sizes, int n_in,
                              void* d_out, int out_size, void* d_ws, size_t ws_size,
                              hipStream_t stream) {
    const float* x     = (const float*)d_in[0];
    const float* w_qkv = (const float*)d_in[1];
    const float* w_out = (const float*)d_in[2];
    float* out = (float*)d_out;

    char* ws = (char*)d_ws;
    unsigned short* qkvb  = (unsigned short*)ws;                 // 12,582,912 B
    unsigned short* attnb = (unsigned short*)(ws + 12582912);    //  4,194,304 B
    float* cSf            = (float*)(ws + 16777216);             //  4,325,376 B  [1024][1056] f32
    unsigned short* cSt   = (unsigned short*)(ws + 21102592);    //  2,162,688 B  [1024][1056] bf16
    // total 23,265,280 B

    // 1) QKV projection + fused per-chunk local sums (phi pre-applied to q,k)
    gemm_qkv_cs<<<NC, 256, 0, stream>>>(x, w_qkv, qkvb, cSf);

    // 2) exclusive prefix over chunks
    chunk_scan<<<132, 256, 0, stream>>>(cSf, cSt);

    // 3) per-chunk outputs -> bf16 attn (plain loads, no phi on this path)
    chunk_out<<<NC, 256, 0, stream>>>(qkvb, cSt, attnb);

    // 4) output projection: 64x64 tiles -> 512 blocks = 2/CU
    gemm_nt<64, 64, false, false><<<dim3(4096 / 64, 512 / 64), 256, 0, stream>>>(
        attnb, w_out, out, 512, 512);
}